// Round 3
// baseline (1178.377 us; speedup 1.0000x reference)
//
#include <hip/hip_runtime.h>

typedef unsigned short u16;
typedef unsigned long long u64;
typedef float f32x4 __attribute__((ext_vector_type(4)));
typedef __bf16 bf16x8 __attribute__((ext_vector_type(8)));

#define T_ 8
#define B_ 16
#define C_ 384
#define N_ 1024
#define HEADS_ 8
#define HD_ 48
#define NC_ 4
#define EPS_ 1e-5f
#define SCALE_ (1.0f / 32.0f)

__device__ __forceinline__ float bf2f(u16 u) {
  union { unsigned int i; float f; } x;
  x.i = ((unsigned int)u) << 16;
  return x.f;
}
__device__ __forceinline__ u16 f2bf(float f) {
  unsigned int u = __float_as_uint(f);
  u += 0x7fffu + ((u >> 16) & 1u);
  return (u16)(u >> 16);
}

__device__ __forceinline__ void glds16(const void* g, void* s) {
  __builtin_amdgcn_global_load_lds(
      (const __attribute__((address_space(1))) void*)g,
      (__attribute__((address_space(3))) void*)s, 16, 0, 0);
}

// ---------------------------------------------------------------------------
// Kernel 0a: convert q/k/v/proj weights f32 -> bf16.  [4][C][C]
// ---------------------------------------------------------------------------
__global__ __launch_bounds__(256) void wconv(const float* __restrict__ a,
                                             const float* __restrict__ b,
                                             const float* __restrict__ c,
                                             const float* __restrict__ d,
                                             u16* __restrict__ o) {
  const int m = blockIdx.x / 72;  // 72 blocks per 384x384 matrix
  const float* s = (m == 0) ? a : (m == 1) ? b : (m == 2) ? c : d;
  const size_t off = (size_t)(blockIdx.x % 72) * 2048 + (size_t)threadIdx.x * 8;
  float4 f0 = *(const float4*)(s + off);
  float4 f1 = *(const float4*)(s + off + 4);
  u16 h[8] = {f2bf(f0.x), f2bf(f0.y), f2bf(f0.z), f2bf(f0.w),
              f2bf(f1.x), f2bf(f1.y), f2bf(f1.z), f2bf(f1.w)};
  *(uint4*)(o + (size_t)m * (C_ * C_) + off) = *(const uint4*)h;
}

// ---------------------------------------------------------------------------
// Kernel 0b: xt[tb][n][c] = bf16(relu(x[tb][c][n]))  (transpose + convert once)
// ---------------------------------------------------------------------------
__global__ __launch_bounds__(256) void prep_xt(const float* __restrict__ x,
                                               u16* __restrict__ xt) {
  const int tb = blockIdx.y;
  const int n = blockIdx.x * 64 + (threadIdx.x & 63);
  const int cg = threadIdx.x >> 6;  // 0..3
  const float* xb = x + (size_t)tb * C_ * N_ + n;
  u16* ob = xt + ((size_t)tb * N_ + n) * C_;
#pragma unroll
  for (int g = 0; g < 12; ++g) {
    int c = (cg + g * 4) * 8;
    u16 h[8];
#pragma unroll
    for (int j = 0; j < 8; ++j)
      h[j] = f2bf(fmaxf(xb[(size_t)(c + j) * N_], 0.f));
    *(uint4*)(ob + c) = *(const uint4*)h;
  }
}

// ---------------------------------------------------------------------------
// Kernel 1: q/k/v projections, 128x128 tile, BK=64, double-buffered LDS.
// Next K-tile's global_load_lds issued BEFORE the MFMA phase; one barrier per
// step (its implicit vmcnt(0) drain lands after MFMA covered the latency).
// ---------------------------------------------------------------------------
__global__ __launch_bounds__(256) void qkv_gemm(
    const u16* __restrict__ xt, const u16* __restrict__ wbf,
    const float* __restrict__ bnq, const float* __restrict__ bnk,
    const float* __restrict__ bnv,
    u16* __restrict__ qo, u16* __restrict__ ko, float* __restrict__ vo) {
  const int tb = blockIdx.z / 3;
  const int pr = blockIdx.z % 3;
  const int n0 = blockIdx.x * 128;
  const int o0 = blockIdx.y * 128;
  const float* bn = (pr == 0) ? bnq : (pr == 1) ? bnk : bnv;
  const u16* wp = wbf + (size_t)pr * (C_ * C_);
  const u16* xb = xt + (size_t)tb * N_ * C_;

  __shared__ u16 As[2 * 128 * 64];  // [o][c], swizzled 16B chunks
  __shared__ u16 Bs[2 * 128 * 64];  // [n][c], swizzled 16B chunks

  const int tid = threadIdx.x;
  const int lane = tid & 63;
  const int wave = tid >> 6;
  const int wr = wave >> 1, wc = wave & 1;
  const int qd = lane >> 4, l15 = lane & 15;

  f32x4 acc[4][4];
#pragma unroll
  for (int i = 0; i < 4; ++i)
#pragma unroll
    for (int j = 0; j < 4; ++j) acc[i][j] = (f32x4){0.f, 0.f, 0.f, 0.f};

  auto stage = [&](int buf, int c0) {
#pragma unroll
    for (int i = 0; i < 4; ++i) {
      const int L = i * 256 + tid;         // chunk id 0..1023
      const int row = L >> 3;
      const int g = (L & 7) ^ (row & 7);   // pre-swizzled source chunk
      glds16(wp + (size_t)(o0 + row) * C_ + c0 + g * 8,
             As + (size_t)buf * (128 * 64) + (size_t)(i * 256 + wave * 64) * 8);
      glds16(xb + (size_t)(n0 + row) * C_ + c0 + g * 8,
             Bs + (size_t)buf * (128 * 64) + (size_t)(i * 256 + wave * 64) * 8);
    }
  };

  stage(0, 0);
  __syncthreads();  // drains prologue glds

  for (int s = 0; s < 6; ++s) {
    const int cur = s & 1;
    if (s < 5) {
      stage(cur ^ 1, (s + 1) * 64);  // overlaps the MFMA phase below
      __builtin_amdgcn_sched_barrier(0);
    }
    const u16* Ac = As + cur * (128 * 64);
    const u16* Bc = Bs + cur * (128 * 64);
#pragma unroll
    for (int kk = 0; kk < 2; ++kk) {
      bf16x8 wf[4], xf[4];
#pragma unroll
      for (int mi = 0; mi < 4; ++mi) {
        int r = wr * 64 + mi * 16 + l15;
        wf[mi] = *(const bf16x8*)(Ac + r * 64 + (((kk * 4 + qd) ^ (r & 7)) * 8));
      }
#pragma unroll
      for (int ni = 0; ni < 4; ++ni) {
        int r = wc * 64 + ni * 16 + l15;
        xf[ni] = *(const bf16x8*)(Bc + r * 64 + (((kk * 4 + qd) ^ (r & 7)) * 8));
      }
      if (pr != 2) {
#pragma unroll
        for (int mi = 0; mi < 4; ++mi)
#pragma unroll
          for (int ni = 0; ni < 4; ++ni)
            acc[mi][ni] = __builtin_amdgcn_mfma_f32_16x16x32_bf16(
                wf[mi], xf[ni], acc[mi][ni], 0, 0, 0);
      } else {
#pragma unroll
        for (int ni = 0; ni < 4; ++ni)
#pragma unroll
          for (int mi = 0; mi < 4; ++mi)
            acc[ni][mi] = __builtin_amdgcn_mfma_f32_16x16x32_bf16(
                xf[ni], wf[mi], acc[ni][mi], 0, 0, 0);
      }
    }
    __syncthreads();  // drains staged glds; syncs reads before next overwrite
  }

  if (pr < 2) {
    u16* out = (pr == 0) ? qo : ko;
#pragma unroll
    for (int mi = 0; mi < 4; ++mi) {
#pragma unroll
      for (int r = 0; r < 4; ++r) {
        int o = o0 + wr * 64 + mi * 16 + qd * 4 + r;
        float inv = bn[o] * rsqrtf(bn[3 * C_ + o] + EPS_);
        float sh = bn[C_ + o] - bn[2 * C_ + o] * inv;
        size_t rowbase = ((size_t)tb * C_ + o) * N_;
#pragma unroll
        for (int ni = 0; ni < 4; ++ni) {
          int n = n0 + wc * 64 + ni * 16 + l15;
          out[rowbase + n] = f2bf(fmaxf(acc[mi][ni][r] * inv + sh, 0.f));
        }
      }
    }
  } else {
#pragma unroll
    for (int bj = 0; bj < 4; ++bj) {
      int o = o0 + wr * 64 + bj * 16 + l15;
      float inv = bn[o] * rsqrtf(bn[3 * C_ + o] + EPS_);
      float sh = bn[C_ + o] - bn[2 * C_ + o] * inv;
      int hh = o / HD_, dd = o % HD_;
      size_t base = (((size_t)tb * HEADS_ + hh) * N_) * HD_ + dd;
#pragma unroll
      for (int ai = 0; ai < 4; ++ai)
#pragma unroll
        for (int r = 0; r < 4; ++r) {
          int n = n0 + wc * 64 + ai * 16 + qd * 4 + r;
          vo[base + (size_t)n * HD_] = fmaxf(acc[ai][bj][r] * inv + sh, 0.f);
        }
    }
  }
}

// ---------------------------------------------------------------------------
// Kernel 2: MFMA attn. part[g2,d,e] = (1/32) * sum_{s in t-chunk} k[s,d]v[s,e]
// ---------------------------------------------------------------------------
__global__ __launch_bounds__(256) void attn_kv(const u16* __restrict__ kk,
                                               const float* __restrict__ vv,
                                               float* __restrict__ part) {
  const int g2 = blockIdx.x;
  const int tc = g2 & 1;
  const int g = g2 >> 1;
  const int h = g & (HEADS_ - 1);
  const int b = (g >> 3) & (B_ - 1);
  const int cI = g >> 7;
  const int t = cI * 2 + tc;
  const int tid = threadIdx.x;
  const int lane = tid & 63;
  const int wave = tid >> 6;
  const int qd = lane >> 4, l15 = lane & 15;

  __shared__ u16 Ks[2][48 * 128];  // [d][s] bf16, 16B chunks ^= (d&7)
  __shared__ u16 Vt[2][48 * 128];  // [e][s] bf16, 16B chunks ^= (e&7)

  const size_t kbase = ((size_t)(t * B_ + b) * C_ + h * HD_) * N_;
  const size_t vbase = ((size_t)(t * B_ + b) * HEADS_ + h) * (size_t)N_ * HD_;
  const int ksc = (tid & 15) ^ ((tid >> 4) & 7);  // pre-swizzled K src chunk

  f32x4 acc[3][3];
#pragma unroll
  for (int m = 0; m < 3; ++m)
#pragma unroll
    for (int n = 0; n < 3; ++n) acc[m][n] = (f32x4){0.f, 0.f, 0.f, 0.f};

  float4 va[3], vb[3];

  auto issue_v = [&](int sb) {
    size_t nb = (size_t)sb * 128;
#pragma unroll
    for (int i = 0; i < 3; ++i) {
      const float* p = vv + vbase + (nb + 2 * lane) * HD_ + (i * 4 + wave) * 4;
      va[i] = *(const float4*)p;
      vb[i] = *(const float4*)(p + HD_);
    }
  };
  auto issue_k = [&](int sb, int bf) {
    size_t nb = (size_t)sb * 128;
#pragma unroll
    for (int i = 0; i < 3; ++i)
      glds16(kk + kbase + (size_t)(i * 16 + (tid >> 4)) * N_ + nb + ksc * 8,
             &Ks[bf][(i * 256 + wave * 64) * 8]);
  };
  auto write_vt = [&](int bf) {
    unsigned* vt = (unsigned*)Vt[bf];
#pragma unroll
    for (int i = 0; i < 3; ++i) {
      int eq = i * 4 + wave;
      const float* fa = (const float*)&va[i];
      const float* fb = (const float*)&vb[i];
#pragma unroll
      for (int j = 0; j < 4; ++j) {
        int e = eq * 4 + j;
        unsigned pk = (unsigned)f2bf(fa[j]) | ((unsigned)f2bf(fb[j]) << 16);
        vt[e * 64 + (((lane >> 2) ^ (e & 7)) << 2) + (lane & 3)] = pk;
      }
    }
  };

  issue_v(0);
  __builtin_amdgcn_sched_barrier(0);
  issue_k(0, 0);
  __builtin_amdgcn_sched_barrier(0);
  write_vt(0);
  __syncthreads();

  for (int sb = 0; sb < 8; ++sb) {
    const int cur = sb & 1;
    if (sb < 7) {
      issue_v(sb + 1);
      __builtin_amdgcn_sched_barrier(0);
      issue_k(sb + 1, cur ^ 1);
      __builtin_amdgcn_sched_barrier(0);
    }
    const u16* kc = Ks[cur];
    const u16* vc = Vt[cur];
    bf16x8 af[3], bfv[3];
#pragma unroll
    for (int m = 0; m < 3; ++m) {
      int d = m * 16 + l15;
      af[m] =
          *(const bf16x8*)(kc + d * 128 + (((wave * 4 + qd) ^ (d & 7)) << 3));
    }
#pragma unroll
    for (int n = 0; n < 3; ++n) {
      int e = n * 16 + l15;
      bfv[n] =
          *(const bf16x8*)(vc + e * 128 + (((wave * 4 + qd) ^ (e & 7)) << 3));
    }
#pragma unroll
    for (int m = 0; m < 3; ++m)
#pragma unroll
      for (int n = 0; n < 3; ++n)
        acc[m][n] = __builtin_amdgcn_mfma_f32_16x16x32_bf16(af[m], bfv[n],
                                                            acc[m][n], 0, 0, 0);
    if (sb < 7) write_vt(cur ^ 1);
    __syncthreads();
  }

  float* red = (float*)&Ks[0][0];
  if (wave >= 2) {
    float* dst = red + (wave - 2) * 2304;
#pragma unroll
    for (int m = 0; m < 3; ++m)
#pragma unroll
      for (int n = 0; n < 3; ++n)
#pragma unroll
        for (int r = 0; r < 4; ++r)
          dst[((m * 3 + n) * 4 + r) * 64 + lane] = acc[m][n][r];
  }
  __syncthreads();
  if (wave < 2) {
    const float* sp = red + wave * 2304;
#pragma unroll
    for (int m = 0; m < 3; ++m)
#pragma unroll
      for (int n = 0; n < 3; ++n)
#pragma unroll
        for (int r = 0; r < 4; ++r)
          acc[m][n][r] += sp[((m * 3 + n) * 4 + r) * 64 + lane];
  }
  __syncthreads();
  if (wave == 1) {
#pragma unroll
    for (int m = 0; m < 3; ++m)
#pragma unroll
      for (int n = 0; n < 3; ++n)
#pragma unroll
        for (int r = 0; r < 4; ++r)
          red[((m * 3 + n) * 4 + r) * 64 + lane] = acc[m][n][r];
  }
  __syncthreads();
  if (wave == 0) {
#pragma unroll
    for (int m = 0; m < 3; ++m)
#pragma unroll
      for (int n = 0; n < 3; ++n)
#pragma unroll
        for (int r = 0; r < 4; ++r) {
          float v = acc[m][n][r] + red[((m * 3 + n) * 4 + r) * 64 + lane];
          int d = m * 16 + qd * 4 + r;
          int e = n * 16 + l15;
          part[(size_t)g2 * 2304 + d * 48 + e] = v * SCALE_;
        }
  }
}

// ---------------------------------------------------------------------------
// Kernel 3: aot[tb][n][h*48+e] = relu( sum_d q[tb,h*48+d,n] * attn[g,d,e] )
// Transposed output so proj_gemm can glds-stage k-contiguous fragments.
// ---------------------------------------------------------------------------
__global__ __launch_bounds__(256) void q_attn(const u16* __restrict__ qq,
                                              const float* __restrict__ part,
                                              u16* __restrict__ aot) {
  const int n0 = blockIdx.x * 64;
  const int z = blockIdx.y;  // t*B*HEADS + b*HEADS + h
  const int h = z % HEADS_;
  const int b = (z / HEADS_) % B_;
  const int t = z / (HEADS_ * B_);
  const int cI = t / 2;
  const int g = (cI * B_ + b) * HEADS_ + h;
  const int tid = threadIdx.x;
  const int nl = tid & 63, eg = tid >> 6, e0 = eg * 12;

  __shared__ float at[48 * 48];
  for (int idx = tid; idx < 48 * 48; idx += 256)
    at[idx] = part[(size_t)(g * 2) * 2304 + idx] +
              part[(size_t)(g * 2 + 1) * 2304 + idx];
  __syncthreads();

  size_t qbase = ((size_t)(t * B_ + b) * C_ + h * HD_) * N_ + n0 + nl;
  float acc[12];
#pragma unroll
  for (int j = 0; j < 12; ++j) acc[j] = 0.f;
  for (int d = 0; d < 48; ++d) {
    float qv = bf2f(qq[qbase + (size_t)d * N_]);
#pragma unroll
    for (int j = 0; j < 12; ++j) acc[j] += qv * at[d * 48 + e0 + j];
  }
  u16 hb[12];
#pragma unroll
  for (int j = 0; j < 12; ++j) hb[j] = f2bf(fmaxf(acc[j], 0.f));
  u16* op = aot + ((size_t)(t * B_ + b) * N_ + n0 + nl) * C_ + h * HD_ + e0;
  const u64* hp = (const u64*)hb;
#pragma unroll
  for (int j = 0; j < 3; ++j) ((u64*)op)[j] = hp[j];
}

// ---------------------------------------------------------------------------
// Kernel 4: proj GEMM + bias + BN + residual, 128x128 dbuf glds structure.
// y = bn(P*ao + pb) + x.  A = proj weights bf16 [o][c]; B = aot [n][c].
// ---------------------------------------------------------------------------
__global__ __launch_bounds__(256) void proj_gemm(
    const u16* __restrict__ aot, const u16* __restrict__ pwbf,
    const float* __restrict__ pb, const float* __restrict__ pbn,
    const float* __restrict__ x, float* __restrict__ y) {
  const int tb = blockIdx.z;
  const int n0 = blockIdx.x * 128;
  const int o0 = blockIdx.y * 128;
  const u16* ab = aot + (size_t)tb * N_ * C_;

  __shared__ u16 As[2 * 128 * 64];
  __shared__ u16 Bs[2 * 128 * 64];

  const int tid = threadIdx.x;
  const int lane = tid & 63;
  const int wave = tid >> 6;
  const int wr = wave >> 1, wc = wave & 1;
  const int qd = lane >> 4, l15 = lane & 15;

  f32x4 acc[4][4];
#pragma unroll
  for (int i = 0; i < 4; ++i)
#pragma unroll
    for (int j = 0; j < 4; ++j) acc[i][j] = (f32x4){0.f, 0.f, 0.f, 0.f};

  auto stage = [&](int buf, int c0) {
#pragma unroll
    for (int i = 0; i < 4; ++i) {
      const int L = i * 256 + tid;
      const int row = L >> 3;
      const int g = (L & 7) ^ (row & 7);
      glds16(pwbf + (size_t)(o0 + row) * C_ + c0 + g * 8,
             As + (size_t)buf * (128 * 64) + (size_t)(i * 256 + wave * 64) * 8);
      glds16(ab + (size_t)(n0 + row) * C_ + c0 + g * 8,
             Bs + (size_t)buf * (128 * 64) + (size_t)(i * 256 + wave * 64) * 8);
    }
  };

  stage(0, 0);
  __syncthreads();

  for (int s = 0; s < 6; ++s) {
    const int cur = s & 1;
    if (s < 5) {
      stage(cur ^ 1, (s + 1) * 64);
      __builtin_amdgcn_sched_barrier(0);
    }
    const u16* Ac = As + cur * (128 * 64);
    const u16* Bc = Bs + cur * (128 * 64);
#pragma unroll
    for (int kk = 0; kk < 2; ++kk) {
      bf16x8 wf[4], xf[4];
#pragma unroll
      for (int mi = 0; mi < 4; ++mi) {
        int r = wr * 64 + mi * 16 + l15;
        wf[mi] = *(const bf16x8*)(Ac + r * 64 + (((kk * 4 + qd) ^ (r & 7)) * 8));
      }
#pragma unroll
      for (int ni = 0; ni < 4; ++ni) {
        int r = wc * 64 + ni * 16 + l15;
        xf[ni] = *(const bf16x8*)(Bc + r * 64 + (((kk * 4 + qd) ^ (r & 7)) * 8));
      }
#pragma unroll
      for (int mi = 0; mi < 4; ++mi)
#pragma unroll
        for (int ni = 0; ni < 4; ++ni)
          acc[mi][ni] = __builtin_amdgcn_mfma_f32_16x16x32_bf16(
              wf[mi], xf[ni], acc[mi][ni], 0, 0, 0);
    }
    __syncthreads();
  }

#pragma unroll
  for (int mi = 0; mi < 4; ++mi) {
#pragma unroll
    for (int r = 0; r < 4; ++r) {
      int o = o0 + wr * 64 + mi * 16 + qd * 4 + r;
      float g = pbn[o], be = pbn[C_ + o];
      float mu = pbn[2 * C_ + o], va = pbn[3 * C_ + o];
      float inv = g * rsqrtf(va + EPS_);
      float add = pb[o] * inv + (be - mu * inv);
      size_t rowbase = ((size_t)tb * C_ + o) * N_;
#pragma unroll
      for (int ni = 0; ni < 4; ++ni) {
        int n = n0 + wc * 64 + ni * 16 + l15;
        float val = acc[mi][ni][r] * inv + add;
        val += x[rowbase + n];  // residual (pre-relu x)
        y[rowbase + n] = val;
      }
    }
  }
}

extern "C" void kernel_launch(void* const* d_in, const int* in_sizes, int n_in,
                              void* d_out, int out_size, void* d_ws,
                              size_t ws_size, hipStream_t stream) {
  const float* x = (const float*)d_in[0];
  const float* q_w = (const float*)d_in[1];
  const float* q_bn = (const float*)d_in[2];
  const float* k_w = (const float*)d_in[3];
  const float* k_bn = (const float*)d_in[4];
  const float* v_w = (const float*)d_in[5];
  const float* v_bn = (const float*)d_in[6];
  const float* p_w = (const float*)d_in[7];
  const float* p_b = (const float*)d_in[8];
  const float* p_bn = (const float*)d_in[9];

  const size_t NELEM = (size_t)T_ * B_ * C_ * N_;  // 50,331,648
  float* y_out = (float*)d_out;          // output 0: y, f32
  float* v_out = y_out + NELEM;          // output 1: v, f32 heads layout

  // y region (4*NELEM bytes) is dead until proj_gemm:
  //   q  (bf16) in first half — dead after q_attn
  //   xt (bf16) in second half — dead after qkv_gemm; attn partials reuse it.
  u16* q_ws = (u16*)y_out;
  u16* xt_ws = q_ws + NELEM;
  float* part_ws = (float*)xt_ws;
  u16* k_ws = (u16*)d_ws;                // k bf16; reused as aot after attn_kv
  u16* wbf = k_ws + NELEM;               // bf16 weights [4][C*C], live all run
  u16* ao_ws = k_ws;

  wconv<<<dim3(288), 256, 0, stream>>>(q_w, k_w, v_w, p_w, wbf);
  prep_xt<<<dim3(16, 128), 256, 0, stream>>>(x, xt_ws);
  qkv_gemm<<<dim3(8, 3, T_ * B_ * 3), 256, 0, stream>>>(
      xt_ws, wbf, q_bn, k_bn, v_bn, q_ws, k_ws, v_out);
  attn_kv<<<dim3(NC_ * B_ * HEADS_ * 2), 256, 0, stream>>>(k_ws, v_out,
                                                           part_ws);
  q_attn<<<dim3(16, T_ * B_ * HEADS_), 256, 0, stream>>>(q_ws, part_ws, ao_ws);
  proj_gemm<<<dim3(8, 3, T_ * B_), 256, 0, stream>>>(
      ao_ws, wbf + 3 * C_ * C_, p_b, p_bn, x, y_out);
}

// Round 4
// 1091.153 us; speedup vs baseline: 1.0799x; 1.0799x over previous
//
#include <hip/hip_runtime.h>

typedef unsigned short u16;
typedef unsigned long long u64;
typedef float f32x4 __attribute__((ext_vector_type(4)));
typedef __bf16 bf16x8 __attribute__((ext_vector_type(8)));

#define T_ 8
#define B_ 16
#define C_ 384
#define N_ 1024
#define HEADS_ 8
#define HD_ 48
#define NC_ 4
#define EPS_ 1e-5f
#define SCALE_ (1.0f / 32.0f)

__device__ __forceinline__ float bf2f(u16 u) {
  union { unsigned int i; float f; } x;
  x.i = ((unsigned int)u) << 16;
  return x.f;
}
__device__ __forceinline__ u16 f2bf(float f) {
  unsigned int u = __float_as_uint(f);
  u += 0x7fffu + ((u >> 16) & 1u);
  return (u16)(u >> 16);
}

__device__ __forceinline__ void glds16(const void* g, void* s) {
  __builtin_amdgcn_global_load_lds(
      (const __attribute__((address_space(1))) void*)g,
      (__attribute__((address_space(3))) void*)s, 16, 0, 0);
}

// ---------------------------------------------------------------------------
// Kernel 0a: convert q/k/v/proj weights f32 -> bf16.  [4][C][C]
// ---------------------------------------------------------------------------
__global__ __launch_bounds__(256) void wconv(const float* __restrict__ a,
                                             const float* __restrict__ b,
                                             const float* __restrict__ c,
                                             const float* __restrict__ d,
                                             u16* __restrict__ o) {
  const int m = blockIdx.x / 72;  // 72 blocks per 384x384 matrix
  const float* s = (m == 0) ? a : (m == 1) ? b : (m == 2) ? c : d;
  const size_t off = (size_t)(blockIdx.x % 72) * 2048 + (size_t)threadIdx.x * 8;
  float4 f0 = *(const float4*)(s + off);
  float4 f1 = *(const float4*)(s + off + 4);
  u16 h[8] = {f2bf(f0.x), f2bf(f0.y), f2bf(f0.z), f2bf(f0.w),
              f2bf(f1.x), f2bf(f1.y), f2bf(f1.z), f2bf(f1.w)};
  *(uint4*)(o + (size_t)m * (C_ * C_) + off) = *(const uint4*)h;
}

// ---------------------------------------------------------------------------
// Kernel 0b: xt[tb][n][c] = bf16(relu(x[tb][c][n]))  (transpose + convert once)
// ---------------------------------------------------------------------------
__global__ __launch_bounds__(256) void prep_xt(const float* __restrict__ x,
                                               u16* __restrict__ xt) {
  const int tb = blockIdx.y;
  const int n = blockIdx.x * 64 + (threadIdx.x & 63);
  const int cg = threadIdx.x >> 6;  // 0..3
  const float* xb = x + (size_t)tb * C_ * N_ + n;
  u16* ob = xt + ((size_t)tb * N_ + n) * C_;
#pragma unroll
  for (int g = 0; g < 12; ++g) {
    int c = (cg + g * 4) * 8;
    u16 h[8];
#pragma unroll
    for (int j = 0; j < 8; ++j)
      h[j] = f2bf(fmaxf(xb[(size_t)(c + j) * N_], 0.f));
    *(uint4*)(ob + c) = *(const uint4*)h;
  }
}

// ---------------------------------------------------------------------------
// Kernel 1: q/k/v projections, 128x128 tile, BK=64, single-buffer glds
// staging (R2-proven: 32KB LDS -> 5 blocks/CU; TLP hides stage latency).
// ---------------------------------------------------------------------------
__global__ __launch_bounds__(256) void qkv_gemm(
    const u16* __restrict__ xt, const u16* __restrict__ wbf,
    const float* __restrict__ bnq, const float* __restrict__ bnk,
    const float* __restrict__ bnv,
    u16* __restrict__ qo, u16* __restrict__ ko, float* __restrict__ vo) {
  const int tb = blockIdx.z / 3;
  const int pr = blockIdx.z % 3;
  const int n0 = blockIdx.x * 128;
  const int o0 = blockIdx.y * 128;
  const float* bn = (pr == 0) ? bnq : (pr == 1) ? bnk : bnv;
  const u16* wp = wbf + (size_t)pr * (C_ * C_);
  const u16* xb = xt + (size_t)tb * N_ * C_;

  __shared__ u16 As[128 * 64];  // [o][c], swizzled 16B chunks
  __shared__ u16 Bs[128 * 64];  // [n][c], swizzled 16B chunks

  const int tid = threadIdx.x;
  const int lane = tid & 63;
  const int wave = tid >> 6;
  const int wr = wave >> 1, wc = wave & 1;
  const int qd = lane >> 4, l15 = lane & 15;

  f32x4 acc[4][4];
#pragma unroll
  for (int i = 0; i < 4; ++i)
#pragma unroll
    for (int j = 0; j < 4; ++j) acc[i][j] = (f32x4){0.f, 0.f, 0.f, 0.f};

  for (int c0 = 0; c0 < C_; c0 += 64) {
    __syncthreads();  // previous-iter LDS reads done
#pragma unroll
    for (int i = 0; i < 4; ++i) {
      const int L = i * 256 + tid;              // chunk id 0..1023
      const int row = L >> 3;
      const int g = (L & 7) ^ (row & 7);        // pre-swizzled source chunk
      glds16(wp + (size_t)(o0 + row) * C_ + c0 + g * 8,
             As + (size_t)(i * 256 + wave * 64) * 8);
      glds16(xb + (size_t)(n0 + row) * C_ + c0 + g * 8,
             Bs + (size_t)(i * 256 + wave * 64) * 8);
    }
    __syncthreads();  // drains vmcnt -> tiles ready
#pragma unroll
    for (int kk = 0; kk < 2; ++kk) {
      bf16x8 wf[4], xf[4];
#pragma unroll
      for (int mi = 0; mi < 4; ++mi) {
        int r = wr * 64 + mi * 16 + l15;
        wf[mi] = *(const bf16x8*)(As + r * 64 + (((kk * 4 + qd) ^ (r & 7)) * 8));
      }
#pragma unroll
      for (int ni = 0; ni < 4; ++ni) {
        int r = wc * 64 + ni * 16 + l15;
        xf[ni] = *(const bf16x8*)(Bs + r * 64 + (((kk * 4 + qd) ^ (r & 7)) * 8));
      }
      if (pr != 2) {
#pragma unroll
        for (int mi = 0; mi < 4; ++mi)
#pragma unroll
          for (int ni = 0; ni < 4; ++ni)
            acc[mi][ni] = __builtin_amdgcn_mfma_f32_16x16x32_bf16(
                wf[mi], xf[ni], acc[mi][ni], 0, 0, 0);
      } else {
#pragma unroll
        for (int ni = 0; ni < 4; ++ni)
#pragma unroll
          for (int mi = 0; mi < 4; ++mi)
            acc[ni][mi] = __builtin_amdgcn_mfma_f32_16x16x32_bf16(
                xf[ni], wf[mi], acc[ni][mi], 0, 0, 0);
      }
    }
  }

  if (pr < 2) {
    u16* out = (pr == 0) ? qo : ko;
#pragma unroll
    for (int mi = 0; mi < 4; ++mi) {
#pragma unroll
      for (int r = 0; r < 4; ++r) {
        int o = o0 + wr * 64 + mi * 16 + qd * 4 + r;
        float inv = bn[o] * rsqrtf(bn[3 * C_ + o] + EPS_);
        float sh = bn[C_ + o] - bn[2 * C_ + o] * inv;
        size_t rowbase = ((size_t)tb * C_ + o) * N_;
#pragma unroll
        for (int ni = 0; ni < 4; ++ni) {
          int n = n0 + wc * 64 + ni * 16 + l15;
          out[rowbase + n] = f2bf(fmaxf(acc[mi][ni][r] * inv + sh, 0.f));
        }
      }
    }
  } else {
#pragma unroll
    for (int bj = 0; bj < 4; ++bj) {
      int o = o0 + wr * 64 + bj * 16 + l15;
      float inv = bn[o] * rsqrtf(bn[3 * C_ + o] + EPS_);
      float sh = bn[C_ + o] - bn[2 * C_ + o] * inv;
      int hh = o / HD_, dd = o % HD_;
      size_t base = (((size_t)tb * HEADS_ + hh) * N_) * HD_ + dd;
#pragma unroll
      for (int ai = 0; ai < 4; ++ai)
#pragma unroll
        for (int r = 0; r < 4; ++r) {
          int n = n0 + wc * 64 + ai * 16 + qd * 4 + r;
          vo[base + (size_t)n * HD_] = fmaxf(acc[ai][bj][r] * inv + sh, 0.f);
        }
    }
  }
}

// ---------------------------------------------------------------------------
// Kernel 2: MFMA attn. part[g2,d,e] = (1/32) * sum_{s in t-chunk} k[s,d]v[s,e]
// ---------------------------------------------------------------------------
__global__ __launch_bounds__(256) void attn_kv(const u16* __restrict__ kk,
                                               const float* __restrict__ vv,
                                               float* __restrict__ part) {
  const int g2 = blockIdx.x;
  const int tc = g2 & 1;
  const int g = g2 >> 1;
  const int h = g & (HEADS_ - 1);
  const int b = (g >> 3) & (B_ - 1);
  const int cI = g >> 7;
  const int t = cI * 2 + tc;
  const int tid = threadIdx.x;
  const int lane = tid & 63;
  const int wave = tid >> 6;
  const int qd = lane >> 4, l15 = lane & 15;

  __shared__ u16 Ks[2][48 * 128];  // [d][s] bf16, 16B chunks ^= (d&7)
  __shared__ u16 Vt[2][48 * 128];  // [e][s] bf16, 16B chunks ^= (e&7)

  const size_t kbase = ((size_t)(t * B_ + b) * C_ + h * HD_) * N_;
  const size_t vbase = ((size_t)(t * B_ + b) * HEADS_ + h) * (size_t)N_ * HD_;
  const int ksc = (tid & 15) ^ ((tid >> 4) & 7);  // pre-swizzled K src chunk

  f32x4 acc[3][3];
#pragma unroll
  for (int m = 0; m < 3; ++m)
#pragma unroll
    for (int n = 0; n < 3; ++n) acc[m][n] = (f32x4){0.f, 0.f, 0.f, 0.f};

  float4 va[3], vb[3];

  auto issue_v = [&](int sb) {
    size_t nb = (size_t)sb * 128;
#pragma unroll
    for (int i = 0; i < 3; ++i) {
      const float* p = vv + vbase + (nb + 2 * lane) * HD_ + (i * 4 + wave) * 4;
      va[i] = *(const float4*)p;
      vb[i] = *(const float4*)(p + HD_);
    }
  };
  auto issue_k = [&](int sb, int bf) {
    size_t nb = (size_t)sb * 128;
#pragma unroll
    for (int i = 0; i < 3; ++i)
      glds16(kk + kbase + (size_t)(i * 16 + (tid >> 4)) * N_ + nb + ksc * 8,
             &Ks[bf][(i * 256 + wave * 64) * 8]);
  };
  auto write_vt = [&](int bf) {
    unsigned* vt = (unsigned*)Vt[bf];
#pragma unroll
    for (int i = 0; i < 3; ++i) {
      int eq = i * 4 + wave;
      const float* fa = (const float*)&va[i];
      const float* fb = (const float*)&vb[i];
#pragma unroll
      for (int j = 0; j < 4; ++j) {
        int e = eq * 4 + j;
        unsigned pk = (unsigned)f2bf(fa[j]) | ((unsigned)f2bf(fb[j]) << 16);
        vt[e * 64 + (((lane >> 2) ^ (e & 7)) << 2) + (lane & 3)] = pk;
      }
    }
  };

  issue_v(0);
  __builtin_amdgcn_sched_barrier(0);
  issue_k(0, 0);
  __builtin_amdgcn_sched_barrier(0);
  write_vt(0);
  __syncthreads();

  for (int sb = 0; sb < 8; ++sb) {
    const int cur = sb & 1;
    if (sb < 7) {
      issue_v(sb + 1);
      __builtin_amdgcn_sched_barrier(0);
      issue_k(sb + 1, cur ^ 1);
      __builtin_amdgcn_sched_barrier(0);
    }
    const u16* kc = Ks[cur];
    const u16* vc = Vt[cur];
    bf16x8 af[3], bfv[3];
#pragma unroll
    for (int m = 0; m < 3; ++m) {
      int d = m * 16 + l15;
      af[m] =
          *(const bf16x8*)(kc + d * 128 + (((wave * 4 + qd) ^ (d & 7)) << 3));
    }
#pragma unroll
    for (int n = 0; n < 3; ++n) {
      int e = n * 16 + l15;
      bfv[n] =
          *(const bf16x8*)(vc + e * 128 + (((wave * 4 + qd) ^ (e & 7)) << 3));
    }
#pragma unroll
    for (int m = 0; m < 3; ++m)
#pragma unroll
      for (int n = 0; n < 3; ++n)
        acc[m][n] = __builtin_amdgcn_mfma_f32_16x16x32_bf16(af[m], bfv[n],
                                                            acc[m][n], 0, 0, 0);
    if (sb < 7) write_vt(cur ^ 1);
    __syncthreads();
  }

  float* red = (float*)&Ks[0][0];
  if (wave >= 2) {
    float* dst = red + (wave - 2) * 2304;
#pragma unroll
    for (int m = 0; m < 3; ++m)
#pragma unroll
      for (int n = 0; n < 3; ++n)
#pragma unroll
        for (int r = 0; r < 4; ++r)
          dst[((m * 3 + n) * 4 + r) * 64 + lane] = acc[m][n][r];
  }
  __syncthreads();
  if (wave < 2) {
    const float* sp = red + wave * 2304;
#pragma unroll
    for (int m = 0; m < 3; ++m)
#pragma unroll
      for (int n = 0; n < 3; ++n)
#pragma unroll
        for (int r = 0; r < 4; ++r)
          acc[m][n][r] += sp[((m * 3 + n) * 4 + r) * 64 + lane];
  }
  __syncthreads();
  if (wave == 1) {
#pragma unroll
    for (int m = 0; m < 3; ++m)
#pragma unroll
      for (int n = 0; n < 3; ++n)
#pragma unroll
        for (int r = 0; r < 4; ++r)
          red[((m * 3 + n) * 4 + r) * 64 + lane] = acc[m][n][r];
  }
  __syncthreads();
  if (wave == 0) {
#pragma unroll
    for (int m = 0; m < 3; ++m)
#pragma unroll
      for (int n = 0; n < 3; ++n)
#pragma unroll
        for (int r = 0; r < 4; ++r) {
          float v = acc[m][n][r] + red[((m * 3 + n) * 4 + r) * 64 + lane];
          int d = m * 16 + qd * 4 + r;
          int e = n * 16 + l15;
          part[(size_t)g2 * 2304 + d * 48 + e] = v * SCALE_;
        }
  }
}

// ---------------------------------------------------------------------------
// Kernel 3: aot[tb][n][h*48+e] = relu( sum_d q[tb,h*48+d,n] * attn[g,d,e] )
// Transposed output so proj_gemm can glds-stage k-contiguous fragments.
// ---------------------------------------------------------------------------
__global__ __launch_bounds__(256) void q_attn(const u16* __restrict__ qq,
                                              const float* __restrict__ part,
                                              u16* __restrict__ aot) {
  const int n0 = blockIdx.x * 64;
  const int z = blockIdx.y;  // t*B*HEADS + b*HEADS + h
  const int h = z % HEADS_;
  const int b = (z / HEADS_) % B_;
  const int t = z / (HEADS_ * B_);
  const int cI = t / 2;
  const int g = (cI * B_ + b) * HEADS_ + h;
  const int tid = threadIdx.x;
  const int nl = tid & 63, eg = tid >> 6, e0 = eg * 12;

  __shared__ float at[48 * 48];
  for (int idx = tid; idx < 48 * 48; idx += 256)
    at[idx] = part[(size_t)(g * 2) * 2304 + idx] +
              part[(size_t)(g * 2 + 1) * 2304 + idx];
  __syncthreads();

  size_t qbase = ((size_t)(t * B_ + b) * C_ + h * HD_) * N_ + n0 + nl;
  float acc[12];
#pragma unroll
  for (int j = 0; j < 12; ++j) acc[j] = 0.f;
  for (int d = 0; d < 48; ++d) {
    float qv = bf2f(qq[qbase + (size_t)d * N_]);
#pragma unroll
    for (int j = 0; j < 12; ++j) acc[j] += qv * at[d * 48 + e0 + j];
  }
  u16 hb[12];
#pragma unroll
  for (int j = 0; j < 12; ++j) hb[j] = f2bf(fmaxf(acc[j], 0.f));
  u16* op = aot + ((size_t)(t * B_ + b) * N_ + n0 + nl) * C_ + h * HD_ + e0;
  const u64* hp = (const u64*)hb;
#pragma unroll
  for (int j = 0; j < 3; ++j) ((u64*)op)[j] = hp[j];
}

// ---------------------------------------------------------------------------
// Kernel 4: proj GEMM + bias + BN + residual, 128x128 single-buffer glds.
// y = bn(P*ao + pb) + x.  A = proj weights bf16 [o][c]; B = aot [n][c].
// ---------------------------------------------------------------------------
__global__ __launch_bounds__(256) void proj_gemm(
    const u16* __restrict__ aot, const u16* __restrict__ pwbf,
    const float* __restrict__ pb, const float* __restrict__ pbn,
    const float* __restrict__ x, float* __restrict__ y) {
  const int tb = blockIdx.z;
  const int n0 = blockIdx.x * 128;
  const int o0 = blockIdx.y * 128;
  const u16* ab = aot + (size_t)tb * N_ * C_;

  __shared__ u16 As[128 * 64];
  __shared__ u16 Bs[128 * 64];

  const int tid = threadIdx.x;
  const int lane = tid & 63;
  const int wave = tid >> 6;
  const int wr = wave >> 1, wc = wave & 1;
  const int qd = lane >> 4, l15 = lane & 15;

  f32x4 acc[4][4];
#pragma unroll
  for (int i = 0; i < 4; ++i)
#pragma unroll
    for (int j = 0; j < 4; ++j) acc[i][j] = (f32x4){0.f, 0.f, 0.f, 0.f};

  for (int c0 = 0; c0 < C_; c0 += 64) {
    __syncthreads();
#pragma unroll
    for (int i = 0; i < 4; ++i) {
      const int L = i * 256 + tid;
      const int row = L >> 3;
      const int g = (L & 7) ^ (row & 7);
      glds16(pwbf + (size_t)(o0 + row) * C_ + c0 + g * 8,
             As + (size_t)(i * 256 + wave * 64) * 8);
      glds16(ab + (size_t)(n0 + row) * C_ + c0 + g * 8,
             Bs + (size_t)(i * 256 + wave * 64) * 8);
    }
    __syncthreads();
#pragma unroll
    for (int kk = 0; kk < 2; ++kk) {
      bf16x8 wf[4], xf[4];
#pragma unroll
      for (int mi = 0; mi < 4; ++mi) {
        int r = wr * 64 + mi * 16 + l15;
        wf[mi] = *(const bf16x8*)(As + r * 64 + (((kk * 4 + qd) ^ (r & 7)) * 8));
      }
#pragma unroll
      for (int ni = 0; ni < 4; ++ni) {
        int r = wc * 64 + ni * 16 + l15;
        xf[ni] = *(const bf16x8*)(Bs + r * 64 + (((kk * 4 + qd) ^ (r & 7)) * 8));
      }
#pragma unroll
      for (int mi = 0; mi < 4; ++mi)
#pragma unroll
        for (int ni = 0; ni < 4; ++ni)
          acc[mi][ni] = __builtin_amdgcn_mfma_f32_16x16x32_bf16(
              wf[mi], xf[ni], acc[mi][ni], 0, 0, 0);
    }
  }

#pragma unroll
  for (int mi = 0; mi < 4; ++mi) {
#pragma unroll
    for (int r = 0; r < 4; ++r) {
      int o = o0 + wr * 64 + mi * 16 + qd * 4 + r;
      float g = pbn[o], be = pbn[C_ + o];
      float mu = pbn[2 * C_ + o], va = pbn[3 * C_ + o];
      float inv = g * rsqrtf(va + EPS_);
      float add = pb[o] * inv + (be - mu * inv);
      size_t rowbase = ((size_t)tb * C_ + o) * N_;
#pragma unroll
      for (int ni = 0; ni < 4; ++ni) {
        int n = n0 + wc * 64 + ni * 16 + l15;
        float val = acc[mi][ni][r] * inv + add;
        val += x[rowbase + n];  // residual (pre-relu x)
        y[rowbase + n] = val;
      }
    }
  }
}

extern "C" void kernel_launch(void* const* d_in, const int* in_sizes, int n_in,
                              void* d_out, int out_size, void* d_ws,
                              size_t ws_size, hipStream_t stream) {
  const float* x = (const float*)d_in[0];
  const float* q_w = (const float*)d_in[1];
  const float* q_bn = (const float*)d_in[2];
  const float* k_w = (const float*)d_in[3];
  const float* k_bn = (const float*)d_in[4];
  const float* v_w = (const float*)d_in[5];
  const float* v_bn = (const float*)d_in[6];
  const float* p_w = (const float*)d_in[7];
  const float* p_b = (const float*)d_in[8];
  const float* p_bn = (const float*)d_in[9];

  const size_t NELEM = (size_t)T_ * B_ * C_ * N_;  // 50,331,648
  float* y_out = (float*)d_out;          // output 0: y, f32
  float* v_out = y_out + NELEM;          // output 1: v, f32 heads layout

  // y region (4*NELEM bytes) is dead until proj_gemm:
  //   q  (bf16) in first half — dead after q_attn
  //   xt (bf16) in second half — dead after qkv_gemm; attn partials reuse it.
  u16* q_ws = (u16*)y_out;
  u16* xt_ws = q_ws + NELEM;
  float* part_ws = (float*)xt_ws;
  u16* k_ws = (u16*)d_ws;                // k bf16; reused as aot after attn_kv
  u16* wbf = k_ws + NELEM;               // bf16 weights [4][C*C], live all run
  u16* ao_ws = k_ws;

  wconv<<<dim3(288), 256, 0, stream>>>(q_w, k_w, v_w, p_w, wbf);
  prep_xt<<<dim3(16, 128), 256, 0, stream>>>(x, xt_ws);
  qkv_gemm<<<dim3(8, 3, T_ * B_ * 3), 256, 0, stream>>>(
      xt_ws, wbf, q_bn, k_bn, v_bn, q_ws, k_ws, v_out);
  attn_kv<<<dim3(NC_ * B_ * HEADS_ * 2), 256, 0, stream>>>(k_ws, v_out,
                                                           part_ws);
  q_attn<<<dim3(16, T_ * B_ * HEADS_), 256, 0, stream>>>(q_ws, part_ws, ao_ws);
  proj_gemm<<<dim3(8, 3, T_ * B_), 256, 0, stream>>>(
      ao_ws, wbf + 3 * C_ * C_, p_b, p_bn, x, y_out);
}